// Round 3
// baseline (148.201 us; speedup 1.0000x reference)
//
#include <hip/hip_runtime.h>

#define NN 32768
#define KK 32
#define DD 128

typedef float v2f __attribute__((ext_vector_type(2)));
typedef float v4f __attribute__((ext_vector_type(4)));
typedef int   v4i __attribute__((ext_vector_type(4)));

// ---------------------------------------------------------------------------
// Prep kernel: fp8_e4m3 table, SPLIT BY D-HALF so each (branch,half) sub-table
// is 2.10 MiB -> fully resident in one XCD's 4-MiB L2 (the full 4.19-MiB
// per-branch table was 105% of L2 and thrashed; rounds 1-2 proved the gather
// loop is miss-latency-bound, not issue-bound).
//   x8 layout: [branch][dhalf][NN][16 uint]  (64 B half-rows)
//   xw[row]  = dot(x[row,:], w)  (fp32, exact op path)
// Block = 256 = 4 waves; wave handles 2 rows (32 lanes/row, 4 elems/lane).
// ---------------------------------------------------------------------------
__global__ __launch_bounds__(256) void prep_kernel(const float* __restrict__ x1,
                                                   const float* __restrict__ x2,
                                                   const float* __restrict__ w,
                                                   unsigned int* __restrict__ x8,
                                                   float* __restrict__ xw) {
    const int wave = threadIdx.x >> 6;
    const int lane = threadIdx.x & 63;
    const int rsel = lane >> 5;
    const int c    = lane & 31;
    const int row  = blockIdx.x * 8 + wave * 2 + rsel;   // 0..2N-1
    const int b    = (row >= NN);
    const int r    = b ? row - NN : row;
    const float* x = (b ? x2 : x1) + (size_t)r * DD;
    const v4f xv = __builtin_nontemporal_load((const v4f*)(x + 4 * c));
    const float4 wv = *(const float4*)(w + 4 * c);

    int packed = __builtin_amdgcn_cvt_pk_fp8_f32(xv.x, xv.y, 0, false);
    packed     = __builtin_amdgcn_cvt_pk_fp8_f32(xv.z, xv.w, packed, true);
    const int dhalf = c >> 4;      // elems 4c..4c+3 -> half = c>>4
    const int cc    = c & 15;      // uint column within the 64-B half-row
    x8[((size_t)(b * 2 + dhalf) * NN + r) * 16 + cc] = (unsigned int)packed;

    float s = xv.x * wv.x + xv.y * wv.y + xv.z * wv.z + xv.w * wv.w;
    #pragma unroll
    for (int m = 16; m >= 1; m >>= 1)
        s += __shfl_xor(s, m, 64);            // reduce within each 32-half
    if (c == 0) xw[row] = s;
}

// ---------------------------------------------------------------------------
// Main kernel: 2048 blocks x 256 threads. Each block owns 64 n-rows of ONE
// (branch, dhalf) combo; combo = (blockIdx%8)>>1 pins each 2.10-MiB half-table
// to a dedicated XCD pair -> gathers are L2 hits. 4 lanes/row x 16 B cover
// the 64-B half-row; per-thread a[16] accumulators; 4-deep gather batches.
// idx/dm are streamed twice (once per half, +17 MB HBM, overlapped); op is
// emitted by half-0 blocks only. Bitwise-identical accumulation order.
// ---------------------------------------------------------------------------
__global__ __launch_bounds__(256) void pgnn_main(
    const uint4* __restrict__ x8,   // [branch][dhalf][NN][4] uint4
    const float* __restrict__ xw,   // [2N]
    const int* __restrict__ idx1, const float* __restrict__ dm1,
    const int* __restrict__ idx2, const float* __restrict__ dm2,
    const float* __restrict__ b_out,
    float* __restrict__ out)
{
    const int g      = blockIdx.x;
    const int xcd    = g & 7;
    const int combo  = xcd >> 1;          // 0..3 = (branch<<1)|half
    const int branch = combo >> 1;
    const int half   = combo & 1;
    const int nb     = (g >> 3) * 2 + (xcd & 1);   // [0, NN/64)

    const uint4* __restrict__ xbh = x8 + (size_t)combo * NN * 4;
    const float* __restrict__ xwb = xw + (size_t)branch * NN;
    const int*   __restrict__ idx = branch ? idx2 : idx1;
    const float* __restrict__ dm  = branch ? dm2  : dm1;
    float* __restrict__ op = out + (size_t)branch * ((size_t)NN * KK + (size_t)NN * DD);
    float* __restrict__ os = op + (size_t)NN * KK;

    __shared__ uint2 s_pair[64][KK + 2];  // .x = row idx, .y = dm bits
                                          // stride 34: 16B-aligned rows

    const int tid = threadIdx.x;
    const int n0  = nb * 64;

    // Stage (idx,dm) for 64 rows x 32 k; half-0 blocks emit op on the way.
    {
        const int rr = tid >> 2;          // 0..63
        const int k8 = (tid & 3) * 8;     // 0,8,16,24
        const size_t off = (size_t)(n0 + rr) * KK + k8;
        const v4i iv0 = __builtin_nontemporal_load((const v4i*)(idx + off));
        const v4i iv1 = __builtin_nontemporal_load((const v4i*)(idx + off + 4));
        const v4f dv0 = __builtin_nontemporal_load((const v4f*)(dm + off));
        const v4f dv1 = __builtin_nontemporal_load((const v4f*)(dm + off + 4));
        uint4* srow = (uint4*)&s_pair[rr][k8];
        srow[0] = make_uint4((unsigned)iv0.x, __float_as_uint(dv0.x),
                             (unsigned)iv0.y, __float_as_uint(dv0.y));
        srow[1] = make_uint4((unsigned)iv0.z, __float_as_uint(dv0.z),
                             (unsigned)iv0.w, __float_as_uint(dv0.w));
        srow[2] = make_uint4((unsigned)iv1.x, __float_as_uint(dv1.x),
                             (unsigned)iv1.y, __float_as_uint(dv1.y));
        srow[3] = make_uint4((unsigned)iv1.z, __float_as_uint(dv1.z),
                             (unsigned)iv1.w, __float_as_uint(dv1.w));
        if (half == 0) {   // block-uniform: no divergence
            const float bb = b_out[0];
            v4f o0 = { dv0.x * xwb[iv0.x] + bb, dv0.y * xwb[iv0.y] + bb,
                       dv0.z * xwb[iv0.z] + bb, dv0.w * xwb[iv0.w] + bb };
            v4f o1 = { dv1.x * xwb[iv1.x] + bb, dv1.y * xwb[iv1.y] + bb,
                       dv1.z * xwb[iv1.z] + bb, dv1.w * xwb[iv1.w] + bb };
            __builtin_nontemporal_store(o0, (v4f*)(op + off));
            __builtin_nontemporal_store(o1, (v4f*)(op + off + 4));
        }
    }
    __syncthreads();

    const int sub = tid >> 2;    // n-row within block: 0..63
    const int h   = tid & 3;     // 16-byte chunk within the 64-B half-row
    const uint2* __restrict__ prow = s_pair[sub];

    float a[16];
    #pragma unroll
    for (int i = 0; i < 16; ++i) a[i] = 0.f;

    #pragma unroll
    for (int kb = 0; kb < KK; kb += 4) {
        // two b128 broadcast reads fetch 4 (idx,dm) pairs
        const uint4 pq0 = *(const uint4*)&prow[kb];
        const uint4 pq1 = *(const uint4*)&prow[kb + 2];
        uint4 u[4];
        u[0] = xbh[pq0.x * 4u + h];
        u[1] = xbh[pq0.z * 4u + h];
        u[2] = xbh[pq1.x * 4u + h];
        u[3] = xbh[pq1.z * 4u + h];
        const float dd4[4] = { __uint_as_float(pq0.y), __uint_as_float(pq0.w),
                               __uint_as_float(pq1.y), __uint_as_float(pq1.w) };
        #pragma unroll
        for (int j = 0; j < 4; ++j) {
            const float d = dd4[j];
            const v2f f0 = __builtin_amdgcn_cvt_pk_f32_fp8((int)u[j].x, false);
            const v2f f1 = __builtin_amdgcn_cvt_pk_f32_fp8((int)u[j].x, true);
            const v2f f2 = __builtin_amdgcn_cvt_pk_f32_fp8((int)u[j].y, false);
            const v2f f3 = __builtin_amdgcn_cvt_pk_f32_fp8((int)u[j].y, true);
            const v2f f4 = __builtin_amdgcn_cvt_pk_f32_fp8((int)u[j].z, false);
            const v2f f5 = __builtin_amdgcn_cvt_pk_f32_fp8((int)u[j].z, true);
            const v2f f6 = __builtin_amdgcn_cvt_pk_f32_fp8((int)u[j].w, false);
            const v2f f7 = __builtin_amdgcn_cvt_pk_f32_fp8((int)u[j].w, true);
            a[0]  += d * f0.x; a[1]  += d * f0.y; a[2]  += d * f1.x; a[3]  += d * f1.y;
            a[4]  += d * f2.x; a[5]  += d * f2.y; a[6]  += d * f3.x; a[7]  += d * f3.y;
            a[8]  += d * f4.x; a[9]  += d * f4.y; a[10] += d * f5.x; a[11] += d * f5.y;
            a[12] += d * f6.x; a[13] += d * f6.y; a[14] += d * f7.x; a[15] += d * f7.y;
        }
    }
    const float inv = 1.0f / KK;
    float* dst = os + (size_t)(n0 + sub) * DD + half * 64 + h * 16;
    v4f o0 = { a[0]  * inv, a[1]  * inv, a[2]  * inv, a[3]  * inv };
    v4f o1 = { a[4]  * inv, a[5]  * inv, a[6]  * inv, a[7]  * inv };
    v4f o2 = { a[8]  * inv, a[9]  * inv, a[10] * inv, a[11] * inv };
    v4f o3 = { a[12] * inv, a[13] * inv, a[14] * inv, a[15] * inv };
    __builtin_nontemporal_store(o0, (v4f*)dst);
    __builtin_nontemporal_store(o1, (v4f*)(dst + 4));
    __builtin_nontemporal_store(o2, (v4f*)(dst + 8));
    __builtin_nontemporal_store(o3, (v4f*)(dst + 12));
}

// ---------------------------------------------------------------------------
// Fallback (ws too small): fused fp32 kernel (correct, unoptimized path).
// ---------------------------------------------------------------------------
__global__ __launch_bounds__(256) void pgnn_fused(
    const float* __restrict__ x1, const int* __restrict__ idx1,
    const float* __restrict__ dm1,
    const float* __restrict__ x2, const int* __restrict__ idx2,
    const float* __restrict__ dm2,
    const float* __restrict__ w, const float* __restrict__ b_out,
    float* __restrict__ out)
{
    const int branch = blockIdx.y;
    const float* __restrict__ x   = branch ? x2   : x1;
    const int*   __restrict__ idx = branch ? idx2 : idx1;
    const float* __restrict__ dm  = branch ? dm2  : dm1;
    float* __restrict__ op = out + (size_t)branch * ((size_t)NN * KK + (size_t)NN * DD);
    float* __restrict__ os = op + (size_t)NN * KK;

    __shared__ int    s_idx[2][KK];
    __shared__ float  s_dm [2][KK];
    __shared__ float  s_dot[2][KK];
    __shared__ float4 s_acc[2][128];

    const int sub = threadIdx.x >> 7;
    const int t   = threadIdx.x & 127;
    const int gg  = t >> 5;
    const int c   = t & 31;
    const int n   = blockIdx.x * 2 + sub;

    if (t < KK) {
        s_idx[sub][t] = idx[(size_t)n * KK + t];
        s_dm [sub][t] = dm [(size_t)n * KK + t];
    }
    const float4 wv = *(const float4*)(w + 4 * c);
    __syncthreads();

    float4 acc = make_float4(0.f, 0.f, 0.f, 0.f);
    #pragma unroll
    for (int k0 = 0; k0 < KK / 4; ++k0) {
        const int   kk  = k0 * 4 + gg;
        const int   r   = s_idx[sub][kk];
        const float dmk = s_dm [sub][kk];
        const float4 v  = *(const float4*)(x + (size_t)r * DD + 4 * c);
        acc.x += dmk * v.x; acc.y += dmk * v.y;
        acc.z += dmk * v.z; acc.w += dmk * v.w;
        float p = v.x * wv.x + v.y * wv.y + v.z * wv.z + v.w * wv.w;
        #pragma unroll
        for (int m = 16; m >= 1; m >>= 1)
            p += __shfl_xor(p, m, 64);
        if (c == 0) s_dot[sub][kk] = p;
    }
    s_acc[sub][t] = acc;
    __syncthreads();

    if (t < KK)
        op[(size_t)n * KK + t] = s_dm[sub][t] * s_dot[sub][t] + b_out[0];
    if (t < 32) {
        const float4 b0 = s_acc[sub][t];
        const float4 b1 = s_acc[sub][32 + t];
        const float4 b2 = s_acc[sub][64 + t];
        const float4 b3 = s_acc[sub][96 + t];
        float4 r;
        r.x = (b0.x + b1.x + b2.x + b3.x) * (1.0f / KK);
        r.y = (b0.y + b1.y + b2.y + b3.y) * (1.0f / KK);
        r.z = (b0.z + b1.z + b2.z + b3.z) * (1.0f / KK);
        r.w = (b0.w + b1.w + b2.w + b3.w) * (1.0f / KK);
        *(float4*)(os + (size_t)n * DD + 4 * t) = r;
    }
}

extern "C" void kernel_launch(void* const* d_in, const int* in_sizes, int n_in,
                              void* d_out, int out_size, void* d_ws, size_t ws_size,
                              hipStream_t stream) {
    const float* x1   = (const float*)d_in[0];
    const int*   idx1 = (const int*)  d_in[1];
    const float* dm1  = (const float*)d_in[2];
    const float* x2   = (const float*)d_in[3];
    const int*   idx2 = (const int*)  d_in[4];
    const float* dm2  = (const float*)d_in[5];
    const float* w    = (const float*)d_in[6];
    const float* b    = (const float*)d_in[7];
    float* out = (float*)d_out;

    const size_t need = (size_t)2 * NN * DD                   // x8: 8.39 MB
                      + (size_t)2 * NN * sizeof(float);       // xw: 0.26 MB
    if (ws_size >= need) {
        unsigned int* x8 = (unsigned int*)d_ws;
        float*        xw = (float*)((char*)d_ws + (size_t)2 * NN * DD);
        prep_kernel<<<dim3(2 * NN / 8), dim3(256), 0, stream>>>(x1, x2, w, x8, xw);
        pgnn_main<<<dim3(2 * NN / 32), dim3(256), 0, stream>>>(
            (const uint4*)x8, xw, idx1, dm1, idx2, dm2, b, out);
    } else {
        pgnn_fused<<<dim3(NN / 2, 2), dim3(256), 0, stream>>>(
            x1, idx1, dm1, x2, idx2, dm2, w, b, out);
    }
}

// Round 4
// 135.264 us; speedup vs baseline: 1.0956x; 1.0956x over previous
//
#include <hip/hip_runtime.h>

#define NN 32768
#define KK 32
#define DD 128

typedef float v2f __attribute__((ext_vector_type(2)));
typedef float v4f __attribute__((ext_vector_type(4)));
typedef int   v4i __attribute__((ext_vector_type(4)));

// ---------------------------------------------------------------------------
// Prep kernel: x8[r,:] = fp8_e4m3(x[r,:]) (128 B/row, per-branch table = 4 MiB)
//              xw[r]   = dot(x[r,:], w)   (fp32, exact op path)
// Block = 256 = 4 waves; wave handles 2 rows (32 lanes/row, 4 elems/lane).
// x is read once (streaming) -> nontemporal.
// ---------------------------------------------------------------------------
__global__ __launch_bounds__(256) void prep_kernel(const float* __restrict__ x1,
                                                   const float* __restrict__ x2,
                                                   const float* __restrict__ w,
                                                   unsigned int* __restrict__ x8,
                                                   float* __restrict__ xw) {
    const int wave = threadIdx.x >> 6;
    const int lane = threadIdx.x & 63;
    const int half = lane >> 5;
    const int c    = lane & 31;
    const int row  = blockIdx.x * 8 + wave * 2 + half;   // 0..2N-1
    const float* x = (row < NN) ? (x1 + (size_t)row * DD)
                                : (x2 + (size_t)(row - NN) * DD);
    const v4f xv = __builtin_nontemporal_load((const v4f*)(x + 4 * c));
    const float4 wv = *(const float4*)(w + 4 * c);

    int packed = __builtin_amdgcn_cvt_pk_fp8_f32(xv.x, xv.y, 0, false);
    packed     = __builtin_amdgcn_cvt_pk_fp8_f32(xv.z, xv.w, packed, true);
    x8[(size_t)row * 32 + c] = (unsigned int)packed;   // regular store: warm L2

    float s = xv.x * wv.x + xv.y * wv.y + xv.z * wv.z + xv.w * wv.w;
    #pragma unroll
    for (int m = 16; m >= 1; m >>= 1)
        s += __shfl_xor(s, m, 64);            // reduce within each 32-half
    if (c == 0) xw[row] = s;
}

// ---------------------------------------------------------------------------
// Main kernel (round-2 structure, REVERTED from the D-split which regressed:
// r3 counters showed Occupancy 15% / VALU 16% / HBM 21% -> half-idle machine
// from half0/half1 imbalance + 61-vs-42 MB write amplification).
// 256 threads = 32 n-rows, 8 lanes/row, 16-B gathers.
// r0 (8x8B) and r1 (4x16B) were identical: both hold 64 B/thread in flight ->
// latency-bound per Little's law. This version batches the gather 8-deep x
// 16 B = 128 B/thread in flight to double sustained gather BW.
// ---------------------------------------------------------------------------
__global__ __launch_bounds__(256) void pgnn_main(
    const uint4* __restrict__ x8,   // [2N, 8] uint4 = 16 fp8 each
    const float* __restrict__ xw,   // [2N]
    const int* __restrict__ idx1, const float* __restrict__ dm1,
    const int* __restrict__ idx2, const float* __restrict__ dm2,
    const float* __restrict__ b_out,
    float* __restrict__ out)
{
    // grid.x = 2 * NN/32 = 2048. xcd = blockIdx%8; xcd 0-3 -> branch 0.
    const int g      = blockIdx.x;
    const int xcd    = g & 7;
    const int branch = xcd >> 2;
    const int nb     = (g >> 3) * 4 + (xcd & 3);     // [0, NN/32)

    const uint4* __restrict__ xb  = x8 + (size_t)branch * NN * 8;
    const float* __restrict__ xwb = xw + (size_t)branch * NN;
    const int*   __restrict__ idx = branch ? idx2 : idx1;
    const float* __restrict__ dm  = branch ? dm2  : dm1;
    float* __restrict__ op = out + (size_t)branch * ((size_t)NN * KK + (size_t)NN * DD);
    float* __restrict__ os = op + (size_t)NN * KK;

    __shared__ uint2 s_pair[32][KK + 2];  // .x = row idx, .y = dm bits
                                          // stride 34: 16B-aligned rows

    const int tid = threadIdx.x;
    const int n0  = nb * 32;

    // Stage (idx,dm) for 32 rows x 32 k and emit op on the way.
    {
        const int rr = tid >> 3;          // 0..31
        const int k4 = (tid & 7) * 4;     // 0,4,...,28
        const size_t off = (size_t)(n0 + rr) * KK + k4;
        const v4i iv = __builtin_nontemporal_load((const v4i*)(idx + off));
        const v4f dv = __builtin_nontemporal_load((const v4f*)(dm + off));
        const float bb = b_out[0];
        v4f o = { dv.x * xwb[iv.x] + bb, dv.y * xwb[iv.y] + bb,
                  dv.z * xwb[iv.z] + bb, dv.w * xwb[iv.w] + bb };
        __builtin_nontemporal_store(o, (v4f*)(op + off));
        uint4* srow = (uint4*)&s_pair[rr][k4];
        srow[0] = make_uint4((unsigned)iv.x, __float_as_uint(dv.x),
                             (unsigned)iv.y, __float_as_uint(dv.y));
        srow[1] = make_uint4((unsigned)iv.z, __float_as_uint(dv.z),
                             (unsigned)iv.w, __float_as_uint(dv.w));
    }
    __syncthreads();

    const int sub = tid >> 3;    // n-row within block: 0..31
    const int h   = tid & 7;     // 16-byte chunk within the 128 B row
    const uint2* __restrict__ prow = s_pair[sub];

    float a[16];
    #pragma unroll
    for (int i = 0; i < 16; ++i) a[i] = 0.f;

    #pragma unroll
    for (int kb = 0; kb < KK; kb += 8) {
        // four b128 broadcast reads fetch 8 (idx,dm) pairs
        const uint4 pq0 = *(const uint4*)&prow[kb];
        const uint4 pq1 = *(const uint4*)&prow[kb + 2];
        const uint4 pq2 = *(const uint4*)&prow[kb + 4];
        const uint4 pq3 = *(const uint4*)&prow[kb + 6];
        uint4 u[8];
        u[0] = xb[pq0.x * 8u + h];
        u[1] = xb[pq0.z * 8u + h];
        u[2] = xb[pq1.x * 8u + h];
        u[3] = xb[pq1.z * 8u + h];
        u[4] = xb[pq2.x * 8u + h];
        u[5] = xb[pq2.z * 8u + h];
        u[6] = xb[pq3.x * 8u + h];
        u[7] = xb[pq3.z * 8u + h];
        const float dd8[8] = { __uint_as_float(pq0.y), __uint_as_float(pq0.w),
                               __uint_as_float(pq1.y), __uint_as_float(pq1.w),
                               __uint_as_float(pq2.y), __uint_as_float(pq2.w),
                               __uint_as_float(pq3.y), __uint_as_float(pq3.w) };
        #pragma unroll
        for (int j = 0; j < 8; ++j) {
            const float d = dd8[j];
            const v2f f0 = __builtin_amdgcn_cvt_pk_f32_fp8((int)u[j].x, false);
            const v2f f1 = __builtin_amdgcn_cvt_pk_f32_fp8((int)u[j].x, true);
            const v2f f2 = __builtin_amdgcn_cvt_pk_f32_fp8((int)u[j].y, false);
            const v2f f3 = __builtin_amdgcn_cvt_pk_f32_fp8((int)u[j].y, true);
            const v2f f4 = __builtin_amdgcn_cvt_pk_f32_fp8((int)u[j].z, false);
            const v2f f5 = __builtin_amdgcn_cvt_pk_f32_fp8((int)u[j].z, true);
            const v2f f6 = __builtin_amdgcn_cvt_pk_f32_fp8((int)u[j].w, false);
            const v2f f7 = __builtin_amdgcn_cvt_pk_f32_fp8((int)u[j].w, true);
            a[0]  += d * f0.x; a[1]  += d * f0.y; a[2]  += d * f1.x; a[3]  += d * f1.y;
            a[4]  += d * f2.x; a[5]  += d * f2.y; a[6]  += d * f3.x; a[7]  += d * f3.y;
            a[8]  += d * f4.x; a[9]  += d * f4.y; a[10] += d * f5.x; a[11] += d * f5.y;
            a[12] += d * f6.x; a[13] += d * f6.y; a[14] += d * f7.x; a[15] += d * f7.y;
        }
    }
    const float inv = 1.0f / KK;
    float* dst = os + (size_t)(n0 + sub) * DD + h * 16;
    v4f o0 = { a[0]  * inv, a[1]  * inv, a[2]  * inv, a[3]  * inv };
    v4f o1 = { a[4]  * inv, a[5]  * inv, a[6]  * inv, a[7]  * inv };
    v4f o2 = { a[8]  * inv, a[9]  * inv, a[10] * inv, a[11] * inv };
    v4f o3 = { a[12] * inv, a[13] * inv, a[14] * inv, a[15] * inv };
    __builtin_nontemporal_store(o0, (v4f*)dst);
    __builtin_nontemporal_store(o1, (v4f*)(dst + 4));
    __builtin_nontemporal_store(o2, (v4f*)(dst + 8));
    __builtin_nontemporal_store(o3, (v4f*)(dst + 12));
}

// ---------------------------------------------------------------------------
// Fallback (ws too small): fused fp32 kernel (correct, unoptimized path).
// ---------------------------------------------------------------------------
__global__ __launch_bounds__(256) void pgnn_fused(
    const float* __restrict__ x1, const int* __restrict__ idx1,
    const float* __restrict__ dm1,
    const float* __restrict__ x2, const int* __restrict__ idx2,
    const float* __restrict__ dm2,
    const float* __restrict__ w, const float* __restrict__ b_out,
    float* __restrict__ out)
{
    const int branch = blockIdx.y;
    const float* __restrict__ x   = branch ? x2   : x1;
    const int*   __restrict__ idx = branch ? idx2 : idx1;
    const float* __restrict__ dm  = branch ? dm2  : dm1;
    float* __restrict__ op = out + (size_t)branch * ((size_t)NN * KK + (size_t)NN * DD);
    float* __restrict__ os = op + (size_t)NN * KK;

    __shared__ int    s_idx[2][KK];
    __shared__ float  s_dm [2][KK];
    __shared__ float  s_dot[2][KK];
    __shared__ float4 s_acc[2][128];

    const int sub = threadIdx.x >> 7;
    const int t   = threadIdx.x & 127;
    const int gg  = t >> 5;
    const int c   = t & 31;
    const int n   = blockIdx.x * 2 + sub;

    if (t < KK) {
        s_idx[sub][t] = idx[(size_t)n * KK + t];
        s_dm [sub][t] = dm [(size_t)n * KK + t];
    }
    const float4 wv = *(const float4*)(w + 4 * c);
    __syncthreads();

    float4 acc = make_float4(0.f, 0.f, 0.f, 0.f);
    #pragma unroll
    for (int k0 = 0; k0 < KK / 4; ++k0) {
        const int   kk  = k0 * 4 + gg;
        const int   r   = s_idx[sub][kk];
        const float dmk = s_dm [sub][kk];
        const float4 v  = *(const float4*)(x + (size_t)r * DD + 4 * c);
        acc.x += dmk * v.x; acc.y += dmk * v.y;
        acc.z += dmk * v.z; acc.w += dmk * v.w;
        float p = v.x * wv.x + v.y * wv.y + v.z * wv.z + v.w * wv.w;
        #pragma unroll
        for (int m = 16; m >= 1; m >>= 1)
            p += __shfl_xor(p, m, 64);
        if (c == 0) s_dot[sub][kk] = p;
    }
    s_acc[sub][t] = acc;
    __syncthreads();

    if (t < KK)
        op[(size_t)n * KK + t] = s_dm[sub][t] * s_dot[sub][t] + b_out[0];
    if (t < 32) {
        const float4 b0 = s_acc[sub][t];
        const float4 b1 = s_acc[sub][32 + t];
        const float4 b2 = s_acc[sub][64 + t];
        const float4 b3 = s_acc[sub][96 + t];
        float4 r;
        r.x = (b0.x + b1.x + b2.x + b3.x) * (1.0f / KK);
        r.y = (b0.y + b1.y + b2.y + b3.y) * (1.0f / KK);
        r.z = (b0.z + b1.z + b2.z + b3.z) * (1.0f / KK);
        r.w = (b0.w + b1.w + b2.w + b3.w) * (1.0f / KK);
        *(float4*)(os + (size_t)n * DD + 4 * t) = r;
    }
}

extern "C" void kernel_launch(void* const* d_in, const int* in_sizes, int n_in,
                              void* d_out, int out_size, void* d_ws, size_t ws_size,
                              hipStream_t stream) {
    const float* x1   = (const float*)d_in[0];
    const int*   idx1 = (const int*)  d_in[1];
    const float* dm1  = (const float*)d_in[2];
    const float* x2   = (const float*)d_in[3];
    const int*   idx2 = (const int*)  d_in[4];
    const float* dm2  = (const float*)d_in[5];
    const float* w    = (const float*)d_in[6];
    const float* b    = (const float*)d_in[7];
    float* out = (float*)d_out;

    const size_t need = (size_t)2 * NN * DD                   // x8: 8.39 MB
                      + (size_t)2 * NN * sizeof(float);       // xw: 0.26 MB
    if (ws_size >= need) {
        unsigned int* x8 = (unsigned int*)d_ws;
        float*        xw = (float*)((char*)d_ws + (size_t)2 * NN * DD);
        prep_kernel<<<dim3(2 * NN / 8), dim3(256), 0, stream>>>(x1, x2, w, x8, xw);
        pgnn_main<<<dim3(2 * NN / 32), dim3(256), 0, stream>>>(
            (const uint4*)x8, xw, idx1, dm1, idx2, dm2, b, out);
    } else {
        pgnn_fused<<<dim3(NN / 2, 2), dim3(256), 0, stream>>>(
            x1, idx1, dm1, x2, idx2, dm2, w, b, out);
    }
}